// Round 1
// baseline (504.795 us; speedup 1.0000x reference)
//
#include <hip/hip_runtime.h>

// Problem constants
constexpr int BB = 1024;   // batch
constexpr int GG = 2000;   // genes
constexpr int SS = 32;     // per-gene width
constexpr int K1 = 4096, K2 = 2048, K3 = 1024;
constexpr int HH = 64;

// workspace layout (in floats)
constexpr int BH      = BB * HH;          // 65536
constexpr int GENE_SZ = BB * GG;          // 2,048,000
constexpr int Y1P_OFF = GENE_SZ;          // 4 slabs
constexpr int Y2P_OFF = Y1P_OFF + 4 * BH; // 2 slabs
constexpr int Y3P_OFF = Y2P_OFF + 2 * BH; // 1 slab

constexpr int NGENE_CHUNKS = 63;          // ceil(2000/32)
constexpr int NB_GRP       = 16;          // 1024/64
constexpr int NGENE_BLK    = NGENE_CHUNKS * NB_GRP; // 1008
constexpr int NGEMM_BLK    = 448;         // 256 (Y1) + 128 (Y2) + 64 (Y3)
constexpr int KCH          = 1024;        // split-K chunk for all three GEMMs

__global__ __launch_bounds__(256, 4) void k1_gene_and_zgemm(
    const float* __restrict__ x,  const float* __restrict__ z1,
    const float* __restrict__ z2, const float* __restrict__ z3,
    const float* __restrict__ Wg, const float* __restrict__ bg,
    const float* __restrict__ W1, const float* __restrict__ W2,
    const float* __restrict__ W3, float* __restrict__ ws)
{
    __shared__ float zt[16 * 64];
    const int bid = blockIdx.x;
    const int t   = threadIdx.x;

    // interleave: period 13 = 4 gemm blocks + 9 gene blocks (112 periods)
    const int per = bid / 13;
    const int off = bid % 13;

    if (off >= 4) {
        // ---------------- gene block: 64 rows x 32 genes ----------------
        const int gid   = per * 9 + (off - 4);        // 0..1007
        const int chunk = gid % NGENE_CHUNKS;
        const int bgrp  = gid / NGENE_CHUNKS;
        const int g0    = chunk * 32;
        const int b0    = bgrp * 64;
        const int g     = g0 + (t >> 3);
        const bool gv   = (g < GG);

        float4 wg4 = make_float4(0.f, 0.f, 0.f, 0.f);
        if (gv) wg4 = ((const float4*)Wg)[g0 * 8 + t];
        float bias = 0.f;
        if (gv && (t & 7) == 0) bias = bg[g];

        const float* xp = gv ? (x + (size_t)b0 * (GG * SS) + g0 * SS + t * 4)
                             : x;  // safe dummy, result multiplied by 0
        float* gene = ws;

        #pragma unroll 4
        for (int i = 0; i < 64; ++i) {
            float4 x4 = *(const float4*)(xp + (size_t)i * (GG * SS));
            float p = x4.x * wg4.x + x4.y * wg4.y + x4.z * wg4.z + x4.w * wg4.w;
            p += __shfl_xor(p, 1);
            p += __shfl_xor(p, 2);
            p += __shfl_xor(p, 4);
            if (gv && (t & 7) == 0)
                gene[(size_t)(b0 + i) * GG + g] = fmaxf(p + bias, 0.f);
        }
    } else {
        // ---------------- z-GEMM block (split-K, partials to ws) ----------------
        const int id = per * 4 + off;                 // 0..447
        const float* z; const float* W; int K; int mt; float* ys; int kbase;
        if (id < 256)      { z = z1; W = W1; K = K1; mt = id >> 2; kbase = (id & 3) * KCH;
                             ys = ws + Y1P_OFF + (size_t)(id & 3) * BH; }
        else if (id < 384) { int l = id - 256; z = z2; W = W2; K = K2; mt = l >> 1; kbase = (l & 1) * KCH;
                             ys = ws + Y2P_OFF + (size_t)(l & 1) * BH; }
        else               { int l = id - 384; z = z3; W = W3; K = K3; mt = l; kbase = 0;
                             ys = ws + Y3P_OFF; }

        const int m0 = mt * 16;
        const int n  = t & 63;
        const int w  = t >> 6;
        const int srow = t >> 4;
        const int scol = (t & 15) * 4;

        float a0 = 0.f, a1 = 0.f, a2 = 0.f, a3 = 0.f;

        for (int kc = 0; kc < KCH / 64; ++kc) {
            const int k0 = kbase + kc * 64;
            *(float4*)&zt[srow * 64 + scol] =
                *(const float4*)&z[(size_t)(m0 + srow) * K + k0 + scol];
            __syncthreads();
            #pragma unroll
            for (int kk = 0; kk < 64; kk += 4) {
                const float* Wp = W + (size_t)(k0 + kk) * 64 + n;
                const float wa = Wp[0], wb = Wp[64], wc = Wp[128], wd = Wp[192];
                const float4 za = *(const float4*)&zt[(w * 4 + 0) * 64 + kk];
                const float4 zb = *(const float4*)&zt[(w * 4 + 1) * 64 + kk];
                const float4 zc = *(const float4*)&zt[(w * 4 + 2) * 64 + kk];
                const float4 zd = *(const float4*)&zt[(w * 4 + 3) * 64 + kk];
                a0 = fmaf(za.w, wd, fmaf(za.z, wc, fmaf(za.y, wb, fmaf(za.x, wa, a0))));
                a1 = fmaf(zb.w, wd, fmaf(zb.z, wc, fmaf(zb.y, wb, fmaf(zb.x, wa, a1))));
                a2 = fmaf(zc.w, wd, fmaf(zc.z, wc, fmaf(zc.y, wb, fmaf(zc.x, wa, a2))));
                a3 = fmaf(zd.w, wd, fmaf(zd.z, wc, fmaf(zd.y, wb, fmaf(zd.x, wa, a3))));
            }
            __syncthreads();
        }
        ys[(size_t)(m0 + w * 4 + 0) * 64 + n] = a0;
        ys[(size_t)(m0 + w * 4 + 1) * 64 + n] = a1;
        ys[(size_t)(m0 + w * 4 + 2) * 64 + n] = a2;
        ys[(size_t)(m0 + w * 4 + 3) * 64 + n] = a3;
    }
}

__global__ __launch_bounds__(256, 4) void k2_fc0_combine_mlp(
    const float* __restrict__ ws,
    const float* __restrict__ W0,  const float* __restrict__ b0v,
    const float* __restrict__ b1v, const float* __restrict__ b2v,
    const float* __restrict__ b3v,
    const float* __restrict__ w1v, const float* __restrict__ w2v,
    const float* __restrict__ w3v,
    const float* __restrict__ fW1, const float* __restrict__ fb1,
    const float* __restrict__ fW2, const float* __restrict__ fb2,
    const float* __restrict__ fW3, const float* __restrict__ fb3,
    float* __restrict__ out)
{
    const float* gene = ws;
    const float* Y1p  = ws + Y1P_OFF;
    const float* Y2p  = ws + Y2P_OFF;
    const float* Y3p  = ws + Y3P_OFF;

    const int t   = threadIdx.x;
    const int n   = t & 63;
    const int w   = t >> 6;
    const int row = blockIdx.x * 4 + w;

    // ---- Y0 = gene[row,:] @ W0  (K = 2000) ----
    float acc = 0.f;
    const float* gp = gene + (size_t)row * GG;
    #pragma unroll 4
    for (int k = 0; k < GG; k += 4) {
        const float4 g4 = *(const float4*)(gp + k);       // wave-uniform broadcast
        const float* Wp = W0 + (size_t)k * 64 + n;        // coalesced 256B/wave
        acc = fmaf(g4.w, Wp[192], fmaf(g4.z, Wp[128],
              fmaf(g4.y, Wp[64],  fmaf(g4.x, Wp[0], acc))));
    }
    const float h0 = fmaxf(acc + b0v[n], 0.f);

    const int rn = row * 64 + n;
    const float y1 = Y1p[rn] + Y1p[BH + rn] + Y1p[2 * BH + rn] + Y1p[3 * BH + rn];
    float d = fmaf(fmaxf(y1 + b1v[n], 0.f), w1v[n], h0);
    const float y2 = Y2p[rn] + Y2p[BH + rn];
    d = fmaf(fmaxf(y2 + b2v[n], 0.f), w2v[n], d);
    const float y3 = Y3p[rn];
    d = fmaf(fmaxf(y3 + b3v[n], 0.f), w3v[n], d);

    // ---- tiny MLP 64->64->64->1 ----
    __shared__ float sd[4][64];
    __shared__ float sh[4][64];
    sd[w][n] = d;
    __syncthreads();
    float a1 = fb1[n];
    #pragma unroll 8
    for (int j = 0; j < 64; ++j) a1 = fmaf(sd[w][j], fW1[j * 64 + n], a1);
    a1 = fmaxf(a1, 0.f);
    sh[w][n] = a1;
    __syncthreads();
    float a2 = fb2[n];
    #pragma unroll 8
    for (int j = 0; j < 64; ++j) a2 = fmaf(sh[w][j], fW2[j * 64 + n], a2);
    a2 = fmaxf(a2, 0.f);

    float v = a2 * fW3[n];
    #pragma unroll
    for (int o = 32; o > 0; o >>= 1) v += __shfl_xor(v, o);
    if (n == 0) out[row] = v + fb3[0];
}

extern "C" void kernel_launch(void* const* d_in, const int* in_sizes, int n_in,
                              void* d_out, int out_size, void* d_ws, size_t ws_size,
                              hipStream_t stream)
{
    const float* x   = (const float*)d_in[0];
    const float* z1  = (const float*)d_in[1];
    const float* z2  = (const float*)d_in[2];
    const float* z3  = (const float*)d_in[3];
    const float* Wg  = (const float*)d_in[4];
    const float* bg  = (const float*)d_in[5];
    const float* W0  = (const float*)d_in[6];
    const float* b0v = (const float*)d_in[7];
    const float* W1  = (const float*)d_in[8];
    const float* b1v = (const float*)d_in[9];
    const float* W2  = (const float*)d_in[10];
    const float* b2v = (const float*)d_in[11];
    const float* W3  = (const float*)d_in[12];
    const float* b3v = (const float*)d_in[13];
    const float* w1v = (const float*)d_in[14];
    const float* w2v = (const float*)d_in[15];
    const float* w3v = (const float*)d_in[16];
    const float* fW1 = (const float*)d_in[17];
    const float* fb1 = (const float*)d_in[18];
    const float* fW2 = (const float*)d_in[19];
    const float* fb2 = (const float*)d_in[20];
    const float* fW3 = (const float*)d_in[21];
    const float* fb3 = (const float*)d_in[22];

    float* ws  = (float*)d_ws;
    float* out = (float*)d_out;

    k1_gene_and_zgemm<<<dim3(NGENE_BLK + NGEMM_BLK), dim3(256), 0, stream>>>(
        x, z1, z2, z3, Wg, bg, W1, W2, W3, ws);

    k2_fc0_combine_mlp<<<dim3(BB / 4), dim3(256), 0, stream>>>(
        ws, W0, b0v, b1v, b2v, b3v, w1v, w2v, w3v,
        fW1, fb1, fW2, fb2, fW3, fb3, out);
}

// Round 2
// 487.957 us; speedup vs baseline: 1.0345x; 1.0345x over previous
//
#include <hip/hip_runtime.h>

// Problem constants
constexpr int BB = 1024;   // batch
constexpr int GG = 2000;   // genes
constexpr int SS = 32;     // per-gene width
constexpr int K1 = 4096, K2 = 2048, K3 = 1024;

constexpr int BH = BB * 64;               // 65536 floats

// workspace layout (floats)
constexpr int Y1P_OFF = 0;                // 4 split-K slabs
constexpr int Y2P_OFF = 4 * BH;           // 2 slabs
constexpr int Y3P_OFF = 6 * BH;           // 1 slab
constexpr int HP_OFF  = 7 * BH;           // 63 fc0 partial chunks [c][row][n]

constexpr int NCH       = 63;             // ceil(2000/32) gene chunks
constexpr int NGENE_BLK = NCH * 16;       // 1008 (16 batch groups of 64 rows)
constexpr int NGEMM_BLK = 224;            // 128 (Y1) + 64 (Y2) + 32 (Y3)
constexpr int KCH       = 1024;           // split-K chunk

// Interleave 2 gemm : 9 gene per period of 11 -> 112 periods = 1232 blocks
__global__ __launch_bounds__(256, 4) void k1_gene_fc0_zgemm(
    const float* __restrict__ x,  const float* __restrict__ z1,
    const float* __restrict__ z2, const float* __restrict__ z3,
    const float* __restrict__ Wg, const float* __restrict__ bg,
    const float* __restrict__ W0,
    const float* __restrict__ W1, const float* __restrict__ W2,
    const float* __restrict__ W3, float* __restrict__ ws)
{
    __shared__ float lds[64 * 32];        // 8 KB, union: gS[64][32] / zt[32][64]
    const int bid = blockIdx.x;
    const int t   = threadIdx.x;
    const int per = bid / 11;
    const int off = bid % 11;

    if (off >= 2) {
        // ---------- gene block: 64 rows x 32 genes, fused fc0 partial ----------
        const int gid   = per * 9 + (off - 2);     // 0..1007
        const int chunk = gid % NCH;
        const int bgrp  = gid / NCH;
        const int g0    = chunk * 32;
        const int b0    = bgrp * 64;
        const int g     = g0 + (t >> 3);
        const bool gv   = (g < GG);

        float4 wg4 = make_float4(0.f, 0.f, 0.f, 0.f);
        if (gv) wg4 = ((const float4*)Wg)[g0 * 8 + t];
        const float bias = (gv && (t & 7) == 0) ? bg[g] : 0.f;

        const float* xp = gv ? (x + (size_t)b0 * (GG * SS) + g0 * SS + t * 4)
                             : x;  // dummy for invalid genes, result forced to 0
        float* gS = lds;                           // [64][32]

        #pragma unroll 4
        for (int i = 0; i < 64; ++i) {
            float4 x4 = *(const float4*)(xp + (size_t)i * (GG * SS));
            float p = x4.x * wg4.x + x4.y * wg4.y + x4.z * wg4.z + x4.w * wg4.w;
            p += __shfl_xor(p, 1);
            p += __shfl_xor(p, 2);
            p += __shfl_xor(p, 4);
            if ((t & 7) == 0)
                gS[i * 32 + (t >> 3)] = gv ? fmaxf(p + bias, 0.f) : 0.f;
        }

        // W0 chunk (32 x 64) into registers: this thread's column n
        const int n = t & 63;
        const int w = t >> 6;
        float w0r[32];
        #pragma unroll
        for (int j = 0; j < 32; ++j) {
            int gj = g0 + j; if (gj >= GG) gj = GG - 1;   // safe read; gS row is 0
            w0r[j] = W0[(size_t)gj * 64 + n];
        }
        __syncthreads();

        // fc0 partial: hp[m][n] = sum_j gS[m][j] * W0[g0+j][n]
        float* hp = ws + HP_OFF + (size_t)chunk * BH + (size_t)b0 * 64;
        #pragma unroll 4
        for (int mi = 0; mi < 16; ++mi) {
            const int m = w * 16 + mi;
            float acc = 0.f;
            #pragma unroll
            for (int jj = 0; jj < 8; ++jj) {
                const float4 g4 = *(const float4*)&gS[m * 32 + jj * 4];  // uniform bcast
                acc = fmaf(g4.w, w0r[jj * 4 + 3], fmaf(g4.z, w0r[jj * 4 + 2],
                      fmaf(g4.y, w0r[jj * 4 + 1], fmaf(g4.x, w0r[jj * 4 + 0], acc))));
            }
            hp[(size_t)m * 64 + n] = acc;
        }
    } else {
        // ---------- z-GEMM block: 32m x 64n tile, 4m x 2n per thread ----------
        const int id = per * 2 + off;              // 0..223
        const float* z; const float* W; int K; int mt; int kslab; float* ys;
        if (id < 128)      { z = z1; W = W1; K = K1; mt = id >> 2; kslab = id & 3;
                             ys = ws + Y1P_OFF + (size_t)kslab * BH; }
        else if (id < 192) { int l = id - 128; z = z2; W = W2; K = K2; mt = l >> 1; kslab = l & 1;
                             ys = ws + Y2P_OFF + (size_t)kslab * BH; }
        else               { int l = id - 192; z = z3; W = W3; K = K3; mt = l; kslab = 0;
                             ys = ws + Y3P_OFF; }

        const int m0    = mt * 32;
        const int kbase = kslab * KCH;
        const int n2    = t & 31;                  // owns cols n2*2, n2*2+1
        const int mq    = t >> 5;                  // owns rows mq*4 .. +3
        float* zt = lds;                           // [32][64]

        float2 acc[4];
        #pragma unroll
        for (int j = 0; j < 4; ++j) acc[j] = make_float2(0.f, 0.f);

        for (int kc = 0; kc < KCH / 64; ++kc) {
            const int k0 = kbase + kc * 64;
            // stage 32x64 z-tile, fully coalesced
            {
                const int i0 = t, i1 = t + 256;
                ((float4*)zt)[i0] = *(const float4*)&z[(size_t)(m0 + (i0 >> 4)) * K + k0 + (i0 & 15) * 4];
                ((float4*)zt)[i1] = *(const float4*)&z[(size_t)(m0 + (i1 >> 4)) * K + k0 + (i1 & 15) * 4];
            }
            __syncthreads();
            #pragma unroll
            for (int kk = 0; kk < 64; kk += 4) {
                const float* Wp = &W[(size_t)(k0 + kk) * 64 + n2 * 2];
                const float2 wv0 = *(const float2*)(Wp);
                const float2 wv1 = *(const float2*)(Wp + 64);
                const float2 wv2 = *(const float2*)(Wp + 128);
                const float2 wv3 = *(const float2*)(Wp + 192);
                #pragma unroll
                for (int j = 0; j < 4; ++j) {
                    const float4 zj = *(const float4*)&zt[(mq * 4 + j) * 64 + kk];
                    acc[j].x = fmaf(zj.x, wv0.x, acc[j].x); acc[j].y = fmaf(zj.x, wv0.y, acc[j].y);
                    acc[j].x = fmaf(zj.y, wv1.x, acc[j].x); acc[j].y = fmaf(zj.y, wv1.y, acc[j].y);
                    acc[j].x = fmaf(zj.z, wv2.x, acc[j].x); acc[j].y = fmaf(zj.z, wv2.y, acc[j].y);
                    acc[j].x = fmaf(zj.w, wv3.x, acc[j].x); acc[j].y = fmaf(zj.w, wv3.y, acc[j].y);
                }
            }
            __syncthreads();
        }
        #pragma unroll
        for (int j = 0; j < 4; ++j)
            *(float2*)&ys[(size_t)(m0 + mq * 4 + j) * 64 + n2 * 2] = acc[j];
    }
}

__global__ __launch_bounds__(256, 4) void k2_combine_mlp(
    const float* __restrict__ ws,
    const float* __restrict__ b0v,
    const float* __restrict__ b1v, const float* __restrict__ b2v,
    const float* __restrict__ b3v,
    const float* __restrict__ w1v, const float* __restrict__ w2v,
    const float* __restrict__ w3v,
    const float* __restrict__ fW1, const float* __restrict__ fb1,
    const float* __restrict__ fW2, const float* __restrict__ fb2,
    const float* __restrict__ fW3, const float* __restrict__ fb3,
    float* __restrict__ out)
{
    const float* Y1p = ws + Y1P_OFF;
    const float* Y2p = ws + Y2P_OFF;
    const float* Y3p = ws + Y3P_OFF;

    const int t   = threadIdx.x;
    const int n   = t & 63;
    const int w   = t >> 6;
    const int row = blockIdx.x * 4 + w;
    const int rn  = row * 64 + n;

    // ---- reduce fc0 partials over 63 gene chunks ----
    float h = 0.f;
    const float* hp = ws + HP_OFF + rn;
    #pragma unroll 9
    for (int c = 0; c < NCH; ++c) h += hp[(size_t)c * BH];
    const float h0 = fmaxf(h + b0v[n], 0.f);

    // ---- reduce z-GEMM split-K partials + weighted fusion ----
    const float y1 = Y1p[rn] + Y1p[BH + rn] + Y1p[2 * BH + rn] + Y1p[3 * BH + rn];
    float d = fmaf(fmaxf(y1 + b1v[n], 0.f), w1v[n], h0);
    const float y2 = Y2p[rn] + Y2p[BH + rn];
    d = fmaf(fmaxf(y2 + b2v[n], 0.f), w2v[n], d);
    const float y3 = Y3p[rn];
    d = fmaf(fmaxf(y3 + b3v[n], 0.f), w3v[n], d);

    // ---- tiny MLP 64->64->64->1 ----
    __shared__ float sd[4][64];
    __shared__ float sh[4][64];
    sd[w][n] = d;
    __syncthreads();
    float a1 = fb1[n];
    #pragma unroll 8
    for (int j = 0; j < 64; ++j) a1 = fmaf(sd[w][j], fW1[j * 64 + n], a1);
    a1 = fmaxf(a1, 0.f);
    sh[w][n] = a1;
    __syncthreads();
    float a2 = fb2[n];
    #pragma unroll 8
    for (int j = 0; j < 64; ++j) a2 = fmaf(sh[w][j], fW2[j * 64 + n], a2);
    a2 = fmaxf(a2, 0.f);

    float v = a2 * fW3[n];
    #pragma unroll
    for (int o = 32; o > 0; o >>= 1) v += __shfl_xor(v, o);
    if (n == 0) out[row] = v + fb3[0];
}

extern "C" void kernel_launch(void* const* d_in, const int* in_sizes, int n_in,
                              void* d_out, int out_size, void* d_ws, size_t ws_size,
                              hipStream_t stream)
{
    const float* x   = (const float*)d_in[0];
    const float* z1  = (const float*)d_in[1];
    const float* z2  = (const float*)d_in[2];
    const float* z3  = (const float*)d_in[3];
    const float* Wg  = (const float*)d_in[4];
    const float* bg  = (const float*)d_in[5];
    const float* W0  = (const float*)d_in[6];
    const float* b0v = (const float*)d_in[7];
    const float* W1  = (const float*)d_in[8];
    const float* b1v = (const float*)d_in[9];
    const float* W2  = (const float*)d_in[10];
    const float* b2v = (const float*)d_in[11];
    const float* W3  = (const float*)d_in[12];
    const float* b3v = (const float*)d_in[13];
    const float* w1v = (const float*)d_in[14];
    const float* w2v = (const float*)d_in[15];
    const float* w3v = (const float*)d_in[16];
    const float* fW1 = (const float*)d_in[17];
    const float* fb1 = (const float*)d_in[18];
    const float* fW2 = (const float*)d_in[19];
    const float* fb2 = (const float*)d_in[20];
    const float* fW3 = (const float*)d_in[21];
    const float* fb3 = (const float*)d_in[22];

    float* ws  = (float*)d_ws;
    float* out = (float*)d_out;

    k1_gene_fc0_zgemm<<<dim3(NGENE_BLK + NGEMM_BLK), dim3(256), 0, stream>>>(
        x, z1, z2, z3, Wg, bg, W0, W1, W2, W3, ws);

    k2_combine_mlp<<<dim3(BB / 4), dim3(256), 0, stream>>>(
        ws, b0v, b1v, b2v, b3v, w1v, w2v, w3v,
        fW1, fb1, fW2, fb2, fW3, fb3, out);
}

// Round 3
// 425.980 us; speedup vs baseline: 1.1850x; 1.1455x over previous
//
#include <hip/hip_runtime.h>

// Problem constants
constexpr int BB = 1024;   // batch
constexpr int GG = 2000;   // genes
constexpr int SS = 32;     // per-gene width
constexpr int K1 = 4096, K2 = 2048, K3 = 1024;

constexpr int BH = BB * 64;               // 65536 floats

// workspace layout (floats)
constexpr int Y1P_OFF = 0;                // 4 split-K slabs
constexpr int Y2P_OFF = 4 * BH;           // 2 slabs
constexpr int Y3P_OFF = 6 * BH;           // 1 slab
constexpr int HP_OFF  = 7 * BH;           // 63 fc0 partial chunks [c][row][n]

constexpr int NCH       = 63;             // ceil(2000/32) gene chunks
constexpr int NGENE_BLK = NCH * 32;       // 2016 (32 batch groups of 32 rows)
constexpr int NGEMM_BLK = 224;            // 128 (Y1) + 64 (Y2) + 32 (Y3)
constexpr int KCH       = 1024;           // split-K chunk

// GEMM blocks first (long-pole compute starts at t=0, spreads over all XCDs),
// then 2016 memory-bound gene blocks stream x behind them.
__global__ __launch_bounds__(256, 8) void k1_gene_fc0_zgemm(
    const float* __restrict__ x,  const float* __restrict__ z1,
    const float* __restrict__ z2, const float* __restrict__ z3,
    const float* __restrict__ Wg, const float* __restrict__ bg,
    const float* __restrict__ W0,
    const float* __restrict__ W1, const float* __restrict__ W2,
    const float* __restrict__ W3, float* __restrict__ ws)
{
    __shared__ float lds[6144];           // 24 KB union: gene gS[32][32] / gemm zt+wt
    const int bid = blockIdx.x;
    const int t   = threadIdx.x;

    if (bid >= NGEMM_BLK) {
        // ---------- gene block: 32 rows x 32 genes, fused fc0 partial ----------
        const int gid   = bid - NGEMM_BLK;         // 0..2015
        const int chunk = gid % NCH;
        const int bgrp  = gid / NCH;               // 0..31
        const int g0    = chunk * 32;
        const int b0    = bgrp * 32;
        const int g     = g0 + (t >> 3);
        const bool gv   = (g < GG);

        float4 wg4 = make_float4(0.f, 0.f, 0.f, 0.f);
        if (gv) wg4 = ((const float4*)Wg)[g0 * 8 + t];
        const float bias = (gv && (t & 7) == 0) ? bg[g] : 0.f;

        const float* xp = gv ? (x + (size_t)b0 * (GG * SS) + g0 * SS + t * 4)
                             : x;  // dummy for invalid genes, result forced to 0
        float* gS = lds;                           // [32][32]

        // load-8-then-reduce-8: 8 loads in flight, 8 independent shuffle chains
        for (int ii = 0; ii < 32; ii += 8) {
            float4 xr[8];
            #pragma unroll
            for (int j = 0; j < 8; ++j)
                xr[j] = *(const float4*)(xp + (size_t)(ii + j) * (GG * SS));
            #pragma unroll
            for (int j = 0; j < 8; ++j) {
                float p = (xr[j].x * wg4.x + xr[j].y * wg4.y)
                        + (xr[j].z * wg4.z + xr[j].w * wg4.w);
                p += __shfl_xor(p, 1);
                p += __shfl_xor(p, 2);
                p += __shfl_xor(p, 4);
                if ((t & 7) == 0)
                    gS[(ii + j) * 32 + (t >> 3)] = gv ? fmaxf(p + bias, 0.f) : 0.f;
            }
        }

        // W0 chunk (32 x 64) into registers: this thread's column n
        const int n = t & 63;
        const int w = t >> 6;
        float w0r[32];
        #pragma unroll
        for (int j = 0; j < 32; ++j) {
            int gj = g0 + j; if (gj >= GG) gj = GG - 1;   // safe read; gS row is 0
            w0r[j] = W0[(size_t)gj * 64 + n];
        }
        __syncthreads();

        // fc0 partial: hp[m][n] = sum_j gS[m][j] * W0[g0+j][n]
        float* hp = ws + HP_OFF + (size_t)chunk * BH + (size_t)b0 * 64;
        #pragma unroll
        for (int mi = 0; mi < 8; ++mi) {
            const int m = w * 8 + mi;
            float acc = 0.f;
            #pragma unroll
            for (int jj = 0; jj < 8; ++jj) {
                const float4 g4 = *(const float4*)&gS[m * 32 + jj * 4];  // uniform bcast
                acc = fmaf(g4.w, w0r[jj * 4 + 3], fmaf(g4.z, w0r[jj * 4 + 2],
                      fmaf(g4.y, w0r[jj * 4 + 1], fmaf(g4.x, w0r[jj * 4 + 0], acc))));
            }
            hp[(size_t)m * 64 + n] = acc;
        }
    } else {
        // ---------- z-GEMM block: 32m x 64n tile, both operands staged in LDS ----------
        const int id = bid;                        // 0..223
        const float* z; const float* W; int K; int mt; int kslab; float* ys;
        if (id < 128)      { z = z1; W = W1; K = K1; mt = id >> 2; kslab = id & 3;
                             ys = ws + Y1P_OFF + (size_t)kslab * BH; }
        else if (id < 192) { int l = id - 128; z = z2; W = W2; K = K2; mt = l >> 1; kslab = l & 1;
                             ys = ws + Y2P_OFF + (size_t)kslab * BH; }
        else               { int l = id - 192; z = z3; W = W3; K = K3; mt = l; kslab = 0;
                             ys = ws + Y3P_OFF; }

        const int m0    = mt * 32;
        const int kbase = kslab * KCH;
        const int n2    = t & 31;                  // owns cols n2*2, n2*2+1
        const int mq    = t >> 5;                  // owns rows mq*4 .. +3
        float* zt = lds;                           // [32][64]  8 KB
        float* wt = lds + 2048;                    // [64][64] 16 KB

        float2 acc[4];
        #pragma unroll
        for (int j = 0; j < 4; ++j) acc[j] = make_float2(0.f, 0.f);

        for (int kc = 0; kc < KCH / 64; ++kc) {
            const int k0 = kbase + kc * 64;
            // stage 32x64 z-tile (2 f4/thread) + 64x64 W-chunk (4 f4/thread), coalesced
            {
                const int i0 = t, i1 = t + 256;
                ((float4*)zt)[i0] = *(const float4*)&z[(size_t)(m0 + (i0 >> 4)) * K + k0 + (i0 & 15) * 4];
                ((float4*)zt)[i1] = *(const float4*)&z[(size_t)(m0 + (i1 >> 4)) * K + k0 + (i1 & 15) * 4];
                #pragma unroll
                for (int r = 0; r < 4; ++r) {
                    const int idx = t + r * 256;           // 0..1023
                    const int row = idx >> 4;
                    const int c4  = (idx & 15) * 4;
                    *(float4*)&wt[row * 64 + c4] =
                        *(const float4*)&W[(size_t)(k0 + row) * 64 + c4];
                }
            }
            __syncthreads();
            #pragma unroll
            for (int kk = 0; kk < 64; kk += 4) {
                const float2 wv0 = *(const float2*)&wt[(kk + 0) * 64 + n2 * 2];
                const float2 wv1 = *(const float2*)&wt[(kk + 1) * 64 + n2 * 2];
                const float2 wv2 = *(const float2*)&wt[(kk + 2) * 64 + n2 * 2];
                const float2 wv3 = *(const float2*)&wt[(kk + 3) * 64 + n2 * 2];
                #pragma unroll
                for (int j = 0; j < 4; ++j) {
                    const float4 zj = *(const float4*)&zt[(mq * 4 + j) * 64 + kk];
                    acc[j].x = fmaf(zj.x, wv0.x, acc[j].x); acc[j].y = fmaf(zj.x, wv0.y, acc[j].y);
                    acc[j].x = fmaf(zj.y, wv1.x, acc[j].x); acc[j].y = fmaf(zj.y, wv1.y, acc[j].y);
                    acc[j].x = fmaf(zj.z, wv2.x, acc[j].x); acc[j].y = fmaf(zj.z, wv2.y, acc[j].y);
                    acc[j].x = fmaf(zj.w, wv3.x, acc[j].x); acc[j].y = fmaf(zj.w, wv3.y, acc[j].y);
                }
            }
            __syncthreads();
        }
        #pragma unroll
        for (int j = 0; j < 4; ++j)
            *(float2*)&ys[(size_t)(m0 + mq * 4 + j) * 64 + n2 * 2] = acc[j];
    }
}

__global__ __launch_bounds__(256, 4) void k2_combine_mlp(
    const float* __restrict__ ws,
    const float* __restrict__ b0v,
    const float* __restrict__ b1v, const float* __restrict__ b2v,
    const float* __restrict__ b3v,
    const float* __restrict__ w1v, const float* __restrict__ w2v,
    const float* __restrict__ w3v,
    const float* __restrict__ fW1, const float* __restrict__ fb1,
    const float* __restrict__ fW2, const float* __restrict__ fb2,
    const float* __restrict__ fW3, const float* __restrict__ fb3,
    float* __restrict__ out)
{
    const float* Y1p = ws + Y1P_OFF;
    const float* Y2p = ws + Y2P_OFF;
    const float* Y3p = ws + Y3P_OFF;

    const int t   = threadIdx.x;
    const int n   = t & 63;
    const int w   = t >> 6;
    const int row = blockIdx.x * 4 + w;
    const int rn  = row * 64 + n;

    // ---- reduce fc0 partials over 63 gene chunks ----
    float h = 0.f;
    const float* hp = ws + HP_OFF + rn;
    #pragma unroll 9
    for (int c = 0; c < NCH; ++c) h += hp[(size_t)c * BH];
    const float h0 = fmaxf(h + b0v[n], 0.f);

    // ---- reduce z-GEMM split-K partials + weighted fusion ----
    const float y1 = Y1p[rn] + Y1p[BH + rn] + Y1p[2 * BH + rn] + Y1p[3 * BH + rn];
    float d = fmaf(fmaxf(y1 + b1v[n], 0.f), w1v[n], h0);
    const float y2 = Y2p[rn] + Y2p[BH + rn];
    d = fmaf(fmaxf(y2 + b2v[n], 0.f), w2v[n], d);
    const float y3 = Y3p[rn];
    d = fmaf(fmaxf(y3 + b3v[n], 0.f), w3v[n], d);

    // ---- tiny MLP 64->64->64->1 ----
    __shared__ float sd[4][64];
    __shared__ float sh[4][64];
    sd[w][n] = d;
    __syncthreads();
    float a1 = fb1[n];
    #pragma unroll 8
    for (int j = 0; j < 64; ++j) a1 = fmaf(sd[w][j], fW1[j * 64 + n], a1);
    a1 = fmaxf(a1, 0.f);
    sh[w][n] = a1;
    __syncthreads();
    float a2 = fb2[n];
    #pragma unroll 8
    for (int j = 0; j < 64; ++j) a2 = fmaf(sh[w][j], fW2[j * 64 + n], a2);
    a2 = fmaxf(a2, 0.f);

    float v = a2 * fW3[n];
    #pragma unroll
    for (int o = 32; o > 0; o >>= 1) v += __shfl_xor(v, o);
    if (n == 0) out[row] = v + fb3[0];
}

extern "C" void kernel_launch(void* const* d_in, const int* in_sizes, int n_in,
                              void* d_out, int out_size, void* d_ws, size_t ws_size,
                              hipStream_t stream)
{
    const float* x   = (const float*)d_in[0];
    const float* z1  = (const float*)d_in[1];
    const float* z2  = (const float*)d_in[2];
    const float* z3  = (const float*)d_in[3];
    const float* Wg  = (const float*)d_in[4];
    const float* bg  = (const float*)d_in[5];
    const float* W0  = (const float*)d_in[6];
    const float* b0v = (const float*)d_in[7];
    const float* W1  = (const float*)d_in[8];
    const float* b1v = (const float*)d_in[9];
    const float* W2  = (const float*)d_in[10];
    const float* b2v = (const float*)d_in[11];
    const float* W3  = (const float*)d_in[12];
    const float* b3v = (const float*)d_in[13];
    const float* w1v = (const float*)d_in[14];
    const float* w2v = (const float*)d_in[15];
    const float* w3v = (const float*)d_in[16];
    const float* fW1 = (const float*)d_in[17];
    const float* fb1 = (const float*)d_in[18];
    const float* fW2 = (const float*)d_in[19];
    const float* fb2 = (const float*)d_in[20];
    const float* fW3 = (const float*)d_in[21];
    const float* fb3 = (const float*)d_in[22];

    float* ws  = (float*)d_ws;
    float* out = (float*)d_out;

    k1_gene_fc0_zgemm<<<dim3(NGEMM_BLK + NGENE_BLK), dim3(256), 0, stream>>>(
        x, z1, z2, z3, Wg, bg, W0, W1, W2, W3, ws);

    k2_combine_mlp<<<dim3(BB / 4), dim3(256), 0, stream>>>(
        ws, b0v, b1v, b2v, b3v, w1v, w2v, w3v,
        fW1, fb1, fW2, fb2, fW3, fb3, out);
}